// Round 1
// baseline (462.584 us; speedup 1.0000x reference)
//
#include <hip/hip_runtime.h>
#include <stdint.h>

typedef unsigned short u16;
typedef u16   u16x4v __attribute__((ext_vector_type(4)));
typedef u16   u16x8v __attribute__((ext_vector_type(8)));
typedef short s16x8v __attribute__((ext_vector_type(8)));
typedef float f32x4v __attribute__((ext_vector_type(4)));
typedef float f32x2v __attribute__((ext_vector_type(2)));

#define DEV static __device__ __forceinline__

// fp32 -> bf16 round-to-nearest-even
DEV u16 f2bf(float f){
  union { float f; unsigned u; } v; v.f = f;
  unsigned r = v.u + 0x7FFFu + ((v.u >> 16) & 1u);
  return (u16)(r >> 16);
}

// Load one MFMA input fragment: elements [k0..k0+3] and [k0+16..k0+19] of a row.
// k-pattern is a bijection over K=32 used identically for A and B -> exact result.
DEV s16x8v ldfrag(const u16* p){
  u16x4v lo = *(const u16x4v*)(p);
  u16x4v hi = *(const u16x4v*)(p + 16);
  union { u16x4v h[2]; s16x8v v; } u;
  u.h[0] = lo; u.h[1] = hi;
  return u.v;
}

DEV f32x4v mfma16(s16x8v a, s16x8v b, f32x4v c){
  return __builtin_amdgcn_mfma_f32_16x16x32_bf16(a, b, c, 0, 0, 0);
}

// ---------------------------------------------------------------------------
// K0: w (8,512,64) fp32 -> wt[n=h*64+k][d] bf16   (262144 elems per tensor)
__global__ __launch_bounds__(256) void k_wt(const float* __restrict__ w, u16* __restrict__ wt){
  int e = blockIdx.x * 256 + threadIdx.x;     // = n*512 + d
  int n = e >> 9, d = e & 511;
  int h = n >> 6, kk = n & 63;
  wt[e] = f2bf(w[h * 32768 + d * 64 + kk]);
}

// ---------------------------------------------------------------------------
// K1: Y[i][n] = sum_d X[i][d] * Wt[n][d],  X fp32 (8192x512), Wt bf16 (512x512), Y bf16
__global__ __launch_bounds__(256) void k_proj(const float* __restrict__ X,
                                              const u16* __restrict__ Wt,
                                              u16* __restrict__ Y){
  __shared__ u16 Xs[64 * 72];
  __shared__ u16 Ws[64 * 72];
  const int t = threadIdx.x;
  const int lane = t & 63, w = t >> 6;
  const int g = lane >> 4, li = lane & 15;
  const int i0 = blockIdx.x * 64;
  const int n0 = blockIdx.y * 64;
  f32x4v acc[4] = {};
  for(int kc = 0; kc < 512; kc += 64){
    __syncthreads();
    // stage X tile (64x64 fp32 -> bf16)
    #pragma unroll
    for(int it = 0; it < 4; ++it){
      int eidx = it * 256 + t, row = eidx >> 4, q4 = eidx & 15;
      f32x4v xv = *(const f32x4v*)(X + (size_t)(i0 + row) * 512 + kc + q4 * 4);
      u16x4v bv; bv[0]=f2bf(xv[0]); bv[1]=f2bf(xv[1]); bv[2]=f2bf(xv[2]); bv[3]=f2bf(xv[3]);
      *(u16x4v*)(Xs + row * 72 + q4 * 4) = bv;
    }
    // stage W tile (64 n-rows x 64 d)
    #pragma unroll
    for(int it = 0; it < 2; ++it){
      int eidx = it * 256 + t, row = eidx >> 3, c8 = eidx & 7;
      u16x8v wv = *(const u16x8v*)(Wt + (size_t)(n0 + row) * 512 + kc + c8 * 8);
      *(u16x8v*)(Ws + row * 72 + c8 * 8) = wv;
    }
    __syncthreads();
    #pragma unroll
    for(int s = 0; s < 2; ++s){
      int k0 = s * 32 + g * 4;
      s16x8v a = ldfrag(Xs + (w * 16 + li) * 72 + k0);
      #pragma unroll
      for(int j = 0; j < 4; ++j){
        s16x8v b = ldfrag(Ws + (j * 16 + li) * 72 + k0);
        acc[j] = mfma16(a, b, acc[j]);
      }
    }
  }
  #pragma unroll
  for(int j = 0; j < 4; ++j)
    #pragma unroll
    for(int r = 0; r < 4; ++r){
      int row = i0 + w * 16 + g * 4 + r;
      int col = n0 + j * 16 + li;
      Y[(size_t)row * 512 + col] = f2bf(acc[j][r]);
    }
}

// ---------------------------------------------------------------------------
// K2: attention per (h,b), 64 q-rows per block, two-pass online softmax.
DEV void stage_k_tile(u16* Ks, const u16* __restrict__ KH, int b, int h, int mc, int t){
  #pragma unroll
  for(int it = 0; it < 2; ++it){
    int eidx = it * 256 + t, row = eidx >> 3, c8 = eidx & 7;
    u16x8v v = *(const u16x8v*)(KH + (size_t)(b * 2048 + mc * 64 + row) * 512 + h * 64 + c8 * 8);
    *(u16x8v*)(Ks + row * 72 + c8 * 8) = v;
  }
}
DEV void stage_v_tileT(u16* Vts, const u16* __restrict__ VH, int b, int h, int mc, int t){
  #pragma unroll
  for(int it = 0; it < 2; ++it){
    int eidx = it * 256 + t, row = eidx >> 3, c8 = eidx & 7;
    u16x8v v = *(const u16x8v*)(VH + (size_t)(b * 2048 + mc * 64 + row) * 512 + h * 64 + c8 * 8);
    #pragma unroll
    for(int e = 0; e < 8; ++e) Vts[(c8 * 8 + e) * 68 + row] = v[e];
  }
}

__global__ __launch_bounds__(256) void k_attn(const u16* __restrict__ QH, const u16* __restrict__ KH,
                                              const u16* __restrict__ VH, u16* __restrict__ XC,
                                              float* __restrict__ ATT){
  __shared__ u16 Ks [64 * 72];
  __shared__ u16 Vts[64 * 68];
  __shared__ u16 Ps [4 * 16 * 72];
  const int t = threadIdx.x, lane = t & 63, w = t >> 6;
  const int g = lane >> 4, li = lane & 15;
  const int lt = blockIdx.x;                 // q tile (0..31)
  const int hb = blockIdx.y;                 // h*4 + b
  const int h = hb >> 2, b = hb & 3;
  const float rtemper = 0.044194173824159216f;  // 1/sqrt(512)

  // Q fragments for this wave's 16 q-rows, held for the whole kernel
  s16x8v aq[2];
  {
    const u16* qp = QH + (size_t)(b * 2048 + lt * 64 + w * 16 + li) * 512 + h * 64;
    aq[0] = ldfrag(qp + 0 * 32 + g * 4);
    aq[1] = ldfrag(qp + 1 * 32 + g * 4);
  }
  float m_run[4], l_run[4];
  #pragma unroll
  for(int r = 0; r < 4; ++r){ m_run[r] = -1e30f; l_run[r] = 0.f; }

  // ---- pass A: online max + sumexp ----
  for(int mc = 0; mc < 32; ++mc){
    __syncthreads();
    stage_k_tile(Ks, KH, b, h, mc, t);
    __syncthreads();
    f32x4v acc[4] = {};
    #pragma unroll
    for(int s = 0; s < 2; ++s){
      int k0 = s * 32 + g * 4;
      #pragma unroll
      for(int j = 0; j < 4; ++j){
        s16x8v bk = ldfrag(Ks + (j * 16 + li) * 72 + k0);
        acc[j] = mfma16(aq[s], bk, acc[j]);
      }
    }
    #pragma unroll
    for(int r = 0; r < 4; ++r){
      float vals[4], mx = -1e30f;
      #pragma unroll
      for(int j = 0; j < 4; ++j){ vals[j] = acc[j][r] * rtemper; mx = fmaxf(mx, vals[j]); }
      #pragma unroll
      for(int off = 1; off < 16; off <<= 1) mx = fmaxf(mx, __shfl_xor(mx, off, 16));
      float nm = fmaxf(m_run[r], mx);
      float s4 = 0.f;
      #pragma unroll
      for(int j = 0; j < 4; ++j) s4 += __expf(vals[j] - nm);
      #pragma unroll
      for(int off = 1; off < 16; off <<= 1) s4 += __shfl_xor(s4, off, 16);
      l_run[r] = l_run[r] * __expf(m_run[r] - nm) + s4;
      m_run[r] = nm;
    }
  }
  float rl[4];
  #pragma unroll
  for(int r = 0; r < 4; ++r) rl[r] = 1.0f / l_run[r];

  // ---- pass B: recompute S, write attn, PV ----
  f32x4v acco[4] = {};
  for(int mc = 0; mc < 32; ++mc){
    __syncthreads();
    stage_k_tile(Ks, KH, b, h, mc, t);
    stage_v_tileT(Vts, VH, b, h, mc, t);
    __syncthreads();
    f32x4v acc[4] = {};
    #pragma unroll
    for(int s = 0; s < 2; ++s){
      int k0 = s * 32 + g * 4;
      #pragma unroll
      for(int j = 0; j < 4; ++j){
        s16x8v bk = ldfrag(Ks + (j * 16 + li) * 72 + k0);
        acc[j] = mfma16(aq[s], bk, acc[j]);
      }
    }
    u16* Pw = Ps + w * 16 * 72;
    float* attb = ATT + ((size_t)hb * 2048 + lt * 64 + w * 16) * 2048 + mc * 64;
    #pragma unroll
    for(int j = 0; j < 4; ++j)
      #pragma unroll
      for(int r = 0; r < 4; ++r){
        float p = __expf(acc[j][r] * rtemper - m_run[r]) * rl[r];
        attb[(size_t)(g * 4 + r) * 2048 + j * 16 + li] = p;
        Pw[(g * 4 + r) * 72 + j * 16 + li] = f2bf(p);
      }
    // PV: A = P (wave-local LDS round trip), B = V^T
    #pragma unroll
    for(int s = 0; s < 2; ++s){
      int k0 = s * 32 + g * 4;
      s16x8v ap = ldfrag(Pw + li * 72 + k0);
      #pragma unroll
      for(int j = 0; j < 4; ++j){
        s16x8v bv = ldfrag(Vts + (j * 16 + li) * 68 + k0);
        acco[j] = mfma16(ap, bv, acco[j]);
      }
    }
  }
  #pragma unroll
  for(int j = 0; j < 4; ++j)
    #pragma unroll
    for(int r = 0; r < 4; ++r){
      int qrow = lt * 64 + w * 16 + g * 4 + r;
      XC[(size_t)(b * 2048 + qrow) * 512 + h * 64 + j * 16 + li] = f2bf(acco[j][r]);
    }
}

// ---------------------------------------------------------------------------
// K3a: Z[i][d] = sum_c Xb[i][c]*proj_w[d][c] + bias[d] + resid[i][d]   (fp32 out)
__global__ __launch_bounds__(256) void k_out_proj(const u16* __restrict__ Xb,
                                                  const float* __restrict__ Wp,
                                                  const float* __restrict__ bias,
                                                  const float* __restrict__ resid,
                                                  float* __restrict__ Z){
  __shared__ u16 Xs[64 * 72];
  __shared__ u16 Ws[64 * 72];
  const int t = threadIdx.x;
  const int lane = t & 63, w = t >> 6;
  const int g = lane >> 4, li = lane & 15;
  const int i0 = blockIdx.x * 64;
  const int n0 = blockIdx.y * 64;
  f32x4v acc[4] = {};
  for(int kc = 0; kc < 512; kc += 64){
    __syncthreads();
    #pragma unroll
    for(int it = 0; it < 2; ++it){
      int eidx = it * 256 + t, row = eidx >> 3, c8 = eidx & 7;
      u16x8v xv = *(const u16x8v*)(Xb + (size_t)(i0 + row) * 512 + kc + c8 * 8);
      *(u16x8v*)(Xs + row * 72 + c8 * 8) = xv;
    }
    #pragma unroll
    for(int it = 0; it < 4; ++it){
      int eidx = it * 256 + t, row = eidx >> 4, q4 = eidx & 15;
      f32x4v wv = *(const f32x4v*)(Wp + (size_t)(n0 + row) * 512 + kc + q4 * 4);
      u16x4v bv; bv[0]=f2bf(wv[0]); bv[1]=f2bf(wv[1]); bv[2]=f2bf(wv[2]); bv[3]=f2bf(wv[3]);
      *(u16x4v*)(Ws + row * 72 + q4 * 4) = bv;
    }
    __syncthreads();
    #pragma unroll
    for(int s = 0; s < 2; ++s){
      int k0 = s * 32 + g * 4;
      s16x8v a = ldfrag(Xs + (w * 16 + li) * 72 + k0);
      #pragma unroll
      for(int j = 0; j < 4; ++j){
        s16x8v b = ldfrag(Ws + (j * 16 + li) * 72 + k0);
        acc[j] = mfma16(a, b, acc[j]);
      }
    }
  }
  #pragma unroll
  for(int j = 0; j < 4; ++j)
    #pragma unroll
    for(int r = 0; r < 4; ++r){
      int row = i0 + w * 16 + g * 4 + r;
      int col = n0 + j * 16 + li;
      Z[(size_t)row * 512 + col] = acc[j][r] + bias[col] + resid[(size_t)row * 512 + col];
    }
}

// ---------------------------------------------------------------------------
// K3b: row LayerNorm, torch semantics: (z-mu)/(std_ddof1 + eps)*a2 + b2
__global__ __launch_bounds__(256) void k_ln(const float* __restrict__ Z,
                                            const float* __restrict__ a2,
                                            const float* __restrict__ b2,
                                            float* __restrict__ out){
  __shared__ float red[8];
  const int i = blockIdx.x, t = threadIdx.x;
  const float* z = Z + (size_t)i * 512;
  f32x2v v = *(const f32x2v*)(z + t * 2);
  float s = v[0] + v[1], sq = v[0] * v[0] + v[1] * v[1];
  #pragma unroll
  for(int off = 1; off < 64; off <<= 1){
    s  += __shfl_xor(s,  off, 64);
    sq += __shfl_xor(sq, off, 64);
  }
  const int wid = t >> 6;
  if((t & 63) == 0){ red[wid] = s; red[4 + wid] = sq; }
  __syncthreads();
  float S  = red[0] + red[1] + red[2] + red[3];
  float SQ = red[4] + red[5] + red[6] + red[7];
  float mu = S * (1.0f / 512.0f);
  float var = (SQ - 512.0f * mu * mu) * (1.0f / 511.0f);
  float sigma = sqrtf(fmaxf(var, 0.0f));
  float rs = 1.0f / (sigma + 1e-3f);
  f32x2v o;
  o[0] = (v[0] - mu) * rs * a2[t * 2]     + b2[t * 2];
  o[1] = (v[1] - mu) * rs * a2[t * 2 + 1] + b2[t * 2 + 1];
  *(f32x2v*)(out + (size_t)i * 512 + t * 2) = o;
}

// ---------------------------------------------------------------------------
extern "C" void kernel_launch(void* const* d_in, const int* in_sizes, int n_in,
                              void* d_out, int out_size, void* d_ws, size_t ws_size,
                              hipStream_t stream){
  const float* q      = (const float*)d_in[0];
  const float* k      = (const float*)d_in[1];
  const float* v      = (const float*)d_in[2];
  const float* w_qs   = (const float*)d_in[3];
  const float* w_ks   = (const float*)d_in[4];
  const float* w_vs   = (const float*)d_in[5];
  const float* proj_w = (const float*)d_in[6];
  const float* proj_b = (const float*)d_in[7];
  const float* a2     = (const float*)d_in[8];
  const float* b2     = (const float*)d_in[9];

  char* ws = (char*)d_ws;
  u16* wt    = (u16*)(ws);                       // 3 * 512*512 bf16 = 1.5 MB
  u16* qh    = (u16*)(ws + 1572864);             // 8192*512 bf16 = 8 MB
  u16* kh    = (u16*)(ws + 9961472);             // 8 MB
  u16* vh    = (u16*)(ws + 18350080);            // 8 MB
  u16* xc    = (u16*)(ws + 26738688);            // 8 MB
  float* zbuf= (float*)(ws + 35127296);          // 16 MB

  float* out = (float*)d_out;                    // (4,2048,512) fp32
  float* att = out + 4194304;                    // (32,2048,2048) fp32

  k_wt<<<dim3(1024), 256, 0, stream>>>(w_qs, wt);
  k_wt<<<dim3(1024), 256, 0, stream>>>(w_ks, wt + 262144);
  k_wt<<<dim3(1024), 256, 0, stream>>>(w_vs, wt + 524288);

  k_proj<<<dim3(128, 8), 256, 0, stream>>>(q, wt,          qh);
  k_proj<<<dim3(128, 8), 256, 0, stream>>>(k, wt + 262144, kh);
  k_proj<<<dim3(128, 8), 256, 0, stream>>>(v, wt + 524288, vh);

  k_attn<<<dim3(32, 32), 256, 0, stream>>>(qh, kh, vh, xc, att);

  k_out_proj<<<dim3(128, 8), 256, 0, stream>>>(xc, proj_w, proj_b, q, zbuf);
  k_ln<<<dim3(8192), 256, 0, stream>>>(zbuf, a2, b2, out);
}